// Round 15
// baseline (240.031 us; speedup 1.0000x reference)
//
#include <hip/hip_runtime.h>
#include <hip/hip_fp16.h>
#include <math.h>

#define NSEG 126
#define PI_F 3.14159265358979323846f

__device__ __forceinline__ unsigned bitrev8(unsigned v) { return __brev(v) >> 24; }
__device__ __forceinline__ unsigned bitrev6(unsigned v) { return __brev(v) >> 26; }
__device__ __forceinline__ float2 cmulc(float2 a, float2 b) {
    return make_float2(a.x*b.x - a.y*b.y, a.x*b.y + a.y*b.x);
}
__device__ __forceinline__ float2 mulmi(float2 a){ return make_float2(a.y, -a.x); }
__device__ __forceinline__ float2 h2f2(unsigned u) {
    __half2 h = __builtin_bit_cast(__half2, u);
    return __half22float2(h);
}
__device__ __forceinline__ unsigned f2h2(float2 v) {
    return __builtin_bit_cast(unsigned, __float22half2_rn(v));
}

// ---------------------------------------------------------------------------
// Fully scalarized v2 FFT (layout p = 4*lane + i, exit var_ki = X[bitrev8(p)]).
// No arrays -> no scratch. Butterflies via macros over NAMED float2 registers.
// ---------------------------------------------------------------------------
#define BFLY(v, W) { float px_=__shfl_xor(v.x,HL), py_=__shfl_xor(v.y,HL); \
  if (up) { float dx_=px_-v.x, dy_=py_-v.y; v=make_float2(dx_*W.x-dy_*W.y, dx_*W.y+dy_*W.x); } \
  else    { v=make_float2(v.x+px_, v.y+py_); } }

#define ROW4(a,b,c,d) BFLY(a,w0) BFLY(b,w1) BFLY(c,w2) BFLY(d,w3)

#define FFT_STAGES(ALL) \
  { const int HL=32; const bool up=(lane&32)!=0; float s_,c_; \
    __sincosf(-PI_F*(float)(lane&31)*(1.0f/32.0f),&s_,&c_); \
    float2 w0=make_float2(c_,s_); \
    float2 w1=cmulc(w0,make_float2(0.99969882f,-0.02454123f)); \
    float2 w2=cmulc(w0,make_float2(0.99879546f,-0.04906767f)); \
    float2 w3=cmulc(w0,make_float2(0.99729046f,-0.07356456f)); ALL } \
  { const int HL=16; const bool up=(lane&16)!=0; float s_,c_; \
    __sincosf(-PI_F*(float)(lane&15)*(1.0f/16.0f),&s_,&c_); \
    float2 w0=make_float2(c_,s_); \
    float2 w1=cmulc(w0,make_float2(0.99879546f,-0.04906767f)); \
    float2 w2=cmulc(w0,make_float2(0.99518473f,-0.09801714f)); \
    float2 w3=cmulc(w0,make_float2(0.98917651f,-0.14673047f)); ALL } \
  { const int HL=8; const bool up=(lane&8)!=0; float s_,c_; \
    __sincosf(-PI_F*(float)(lane&7)*(1.0f/8.0f),&s_,&c_); \
    float2 w0=make_float2(c_,s_); \
    float2 w1=cmulc(w0,make_float2(0.99518473f,-0.09801714f)); \
    float2 w2=cmulc(w0,make_float2(0.98078528f,-0.19509032f)); \
    float2 w3=cmulc(w0,make_float2(0.95694034f,-0.29028468f)); ALL } \
  { const int HL=4; const bool up=(lane&4)!=0; float s_,c_; \
    __sincosf(-PI_F*(float)(lane&3)*(1.0f/4.0f),&s_,&c_); \
    float2 w0=make_float2(c_,s_); \
    float2 w1=cmulc(w0,make_float2(0.98078528f,-0.19509032f)); \
    float2 w2=cmulc(w0,make_float2(0.92387953f,-0.38268343f)); \
    float2 w3=cmulc(w0,make_float2(0.83146961f,-0.55557023f)); ALL } \
  { const int HL=2; const bool up=(lane&2)!=0; \
    float2 w0=(lane&1)?make_float2(0.f,-1.f):make_float2(1.f,0.f); \
    float2 w1=cmulc(w0,make_float2(0.92387953f,-0.38268343f)); \
    float2 w2=cmulc(w0,make_float2(0.70710678f,-0.70710678f)); \
    float2 w3=cmulc(w0,make_float2(0.38268343f,-0.92387953f)); ALL } \
  { const int HL=1; const bool up=(lane&1)!=0; \
    float2 w0=make_float2(1.f,0.f); \
    float2 w1=make_float2(0.70710678f,-0.70710678f); \
    float2 w2=make_float2(0.f,-1.f); \
    float2 w3=make_float2(-0.70710678f,-0.70710678f); ALL }

#define FIN(a0,a1,a2,a3) { float2 u_,v_; \
  u_=a0; v_=a2; a0=make_float2(u_.x+v_.x,u_.y+v_.y); a2=make_float2(u_.x-v_.x,u_.y-v_.y); \
  u_=a1; v_=a3; a1=make_float2(u_.x+v_.x,u_.y+v_.y); a3=mulmi(make_float2(u_.x-v_.x,u_.y-v_.y)); \
  u_=a0; v_=a1; a0=make_float2(u_.x+v_.x,u_.y+v_.y); a1=make_float2(u_.x-v_.x,u_.y-v_.y); \
  u_=a2; v_=a3; a2=make_float2(u_.x+v_.x,u_.y+v_.y); a3=make_float2(u_.x-v_.x,u_.y-v_.y); }

// ---------------------------------------------------------------------------
// Fused prep (R11 format): bucket j = 255-c; pack r | mirror(r)<<8 | seg<<16.
// ---------------------------------------------------------------------------
__global__ __launch_bounds__(1024) void prep_all(
    const int* __restrict__ rr, const int* __restrict__ cc,
    const int* __restrict__ seg, int n,
    int* __restrict__ starts, int* __restrict__ b_pack, float* __restrict__ acc)
{
    __shared__ int cnt[128];
    __shared__ int cur[128];
    int tid = threadIdx.x;
    if (tid < NSEG * 3) acc[tid] = 0.f;
    if (tid < 128) cnt[tid] = 0;
    __syncthreads();
    for (int i = tid; i < n; i += 1024) {
        int c = cc[i], r = rr[i];
        if ((c > 128) || (c == 128 && r > 128)) atomicAdd(&cnt[255 - c], 1);
    }
    __syncthreads();
    if (tid < 64) {
        int2 c2 = reinterpret_cast<const int2*>(cnt)[tid];
        int lsum = c2.x + c2.y;
        int pre = lsum;
        #pragma unroll
        for (int off = 1; off < 64; off <<= 1) {
            int v = __shfl_up(pre, off);
            if (tid >= off) pre += v;
        }
        int excl = pre - lsum;
        int2 outv = make_int2(excl, excl + c2.x);
        reinterpret_cast<int2*>(cur)[tid] = outv;
        reinterpret_cast<int2*>(starts)[tid] = outv;
        if (tid == 63) starts[128] = excl + c2.x + c2.y;
    }
    __syncthreads();
    for (int i = tid; i < n; i += 1024) {
        int c = cc[i], r = rr[i];
        if ((c > 128) || (c == 128 && r > 128)) {
            int j = 255 - c;
            int pos = atomicAdd(&cur[j], 1);
            b_pack[pos] = r | (((256 - r) & 255) << 8) | (seg[i] << 16);
        }
    }
}

// ---------------------------------------------------------------------------
// Row-pass: scalarized v2 FFT (16 named regs), float4 loads, fp16 Gt.
// ---------------------------------------------------------------------------
#define ALL4 ROW4(x00,x01,x02,x03) ROW4(x10,x11,x12,x13) \
             ROW4(x20,x21,x22,x23) ROW4(x30,x31,x32,x33)

__global__ __launch_bounds__(512, 1) void rowfft_kernel(
    const float* __restrict__ inp, const float* __restrict__ tgt,
    unsigned* __restrict__ G, int pair_base)
{
    __shared__ unsigned T[256 * 17];             // 17408 B
    int tid    = threadIdx.x;
    int wv     = tid >> 6;
    int lane   = tid & 63;
    int plocal = blockIdx.x >> 3;
    int rowgrp = blockIdx.x & 7;
    int row0   = (rowgrp << 5) + (wv << 2);
    size_t base = (((size_t)(pair_base + plocal)) << 16) + ((size_t)row0 << 8);
    const float4* s1 = (const float4*)(inp + base);
    const float4* s2 = (const float4*)(tgt + base);

    float4 A0 = s1[lane],       B0 = s2[lane];
    float4 A1 = s1[64 + lane],  B1 = s2[64 + lane];
    float4 A2 = s1[128 + lane], B2 = s2[128 + lane];
    float4 A3 = s1[192 + lane], B3 = s2[192 + lane];
    float2 x00 = make_float2(A0.x, B0.x), x01 = make_float2(A0.y, B0.y),
           x02 = make_float2(A0.z, B0.z), x03 = make_float2(A0.w, B0.w);
    float2 x10 = make_float2(A1.x, B1.x), x11 = make_float2(A1.y, B1.y),
           x12 = make_float2(A1.z, B1.z), x13 = make_float2(A1.w, B1.w);
    float2 x20 = make_float2(A2.x, B2.x), x21 = make_float2(A2.y, B2.y),
           x22 = make_float2(A2.z, B2.z), x23 = make_float2(A2.w, B2.w);
    float2 x30 = make_float2(A3.x, B3.x), x31 = make_float2(A3.y, B3.y),
           x32 = make_float2(A3.z, B3.z), x33 = make_float2(A3.w, B3.w);

    FFT_STAGES(ALL4)
    FIN(x00,x01,x02,x03) FIN(x10,x11,x12,x13)
    FIN(x20,x21,x22,x23) FIN(x30,x31,x32,x33)

    unsigned* dst = G + (((size_t)plocal) << 16) + (rowgrp << 5);
    #pragma unroll
    for (int pass = 0; pass < 2; pass++) {
        if ((wv >> 2) == pass) {
            int xr = ((wv & 3) << 2);
            unsigned* Tp = &T[(4 * lane) * 17 + xr];
            Tp[0]  = f2h2(x00); Tp[17] = f2h2(x01); Tp[34] = f2h2(x02); Tp[51] = f2h2(x03);
            Tp[1]  = f2h2(x10); Tp[18] = f2h2(x11); Tp[35] = f2h2(x12); Tp[52] = f2h2(x13);
            Tp[2]  = f2h2(x20); Tp[19] = f2h2(x21); Tp[36] = f2h2(x22); Tp[53] = f2h2(x23);
            Tp[3]  = f2h2(x30); Tp[20] = f2h2(x31); Tp[37] = f2h2(x32); Tp[54] = f2h2(x33);
        }
        __syncthreads();
        int xl = tid & 15;
        int qq = tid >> 4;
        #pragma unroll
        for (int ii = 0; ii < 8; ii++) {
            int q = qq + (ii << 5);
            dst[q * 256 + (pass << 4) + xl] = T[q * 17 + xl];
        }
        __syncthreads();
    }
}

// ---------------------------------------------------------------------------
// Column-pass + gather: scalarized (32 named regs), geometry identical to R14.
// ---------------------------------------------------------------------------
#define ALL8 ROW4(x00,x01,x02,x03) ROW4(x10,x11,x12,x13) \
             ROW4(x20,x21,x22,x23) ROW4(x30,x31,x32,x33) \
             ROW4(x40,x41,x42,x43) ROW4(x50,x51,x52,x53) \
             ROW4(x60,x61,x62,x63) ROW4(x70,x71,x72,x73)

#define STORE_GATHER(t, A0,A1,A2,A3, B0,B1,B2,B3) { \
    slot[nb]       = A0; slot[nb + 128]       = A1; \
    slot[nb + 64]  = A2; slot[nb + 192]       = A3; \
    slot[256 + nb] = B0; slot[256 + nb + 128] = B1; \
    slot[256 + nb + 64] = B2; slot[256 + nb + 192] = B3; \
    int j_ = jb0 + (t); \
    int s0_ = starts[j_], s1_ = starts[j_ + 1]; \
    int e_  = s0_ + lane; \
    int pk_ = (e_ < s1_) ? b_pack[e_] : 0; \
    while (e_ < s1_) { \
        int e2_  = e_ + 64; \
        int pk2_ = (e2_ < s1_) ? b_pack[e2_] : 0; \
        float2 a_ = slot[256 + (pk_ & 255)]; \
        float2 m_ = slot[(pk_ >> 8) & 255]; \
        int sg_ = pk_ >> 16; \
        float f1x_ = a_.x + m_.x, f1y_ = a_.y - m_.y; \
        float dx_  = a_.x - m_.x, dy_  = a_.y + m_.y; \
        atomicAdd(&accl[sg_ * 3 + 0], f1x_ * dy_ - f1y_ * dx_); \
        atomicAdd(&accl[sg_ * 3 + 1], f1x_ * f1x_ + f1y_ * f1y_); \
        atomicAdd(&accl[sg_ * 3 + 2], dx_ * dx_ + dy_ * dy_); \
        e_ = e2_; pk_ = pk2_; \
    } }

__global__ __launch_bounds__(512, 1) void colfft_gather_kernel(
    const unsigned* __restrict__ G, const int* __restrict__ starts,
    const int* __restrict__ b_pack, float* __restrict__ acc)
{
    __shared__ float2 Fb[8 * 512];               // 32 KiB
    __shared__ float accl[NSEG * 3];
    int tid    = threadIdx.x;
    int wv     = tid >> 6;
    int lane   = tid & 63;
    int plocal = blockIdx.x >> 2;
    int b      = blockIdx.x & 3;
    int jb0    = (b << 5) + (wv << 2);

    for (int i = tid; i < NSEG * 3; i += 512) accl[i] = 0.f;
    __syncthreads();

    const unsigned* Gp = G + (((size_t)plocal) << 16);
    const uint4* cA = (const uint4*)(Gp + ((size_t)bitrev8((unsigned)(jb0 + 1)) << 8));
    const uint4* cB = (const uint4*)(Gp + ((size_t)bitrev8((unsigned)(255 - jb0)) << 8));
    const uint4* cC = (const uint4*)(Gp + ((size_t)bitrev8((unsigned)(jb0 + 2)) << 8));
    const uint4* cD = (const uint4*)(Gp + ((size_t)bitrev8((unsigned)(254 - jb0)) << 8));
    const uint4* cE = (const uint4*)(Gp + ((size_t)bitrev8((unsigned)(jb0 + 3)) << 8));
    const uint4* cF = (const uint4*)(Gp + ((size_t)bitrev8((unsigned)(253 - jb0)) << 8));
    const uint4* cG = (const uint4*)(Gp + ((size_t)bitrev8((unsigned)(jb0 + 4)) << 8));
    const uint4* cH = (const uint4*)(Gp + ((size_t)bitrev8((unsigned)(252 - jb0)) << 8));
    uint4 rA = cA[lane], rB = cB[lane], rC = cC[lane], rD = cD[lane];
    uint4 rE = cE[lane], rF = cF[lane], rG = cG[lane], rH = cH[lane];

    float2 x00 = h2f2(rA.x), x01 = h2f2(rA.y), x02 = h2f2(rA.z), x03 = h2f2(rA.w);
    float2 x10 = h2f2(rB.x), x11 = h2f2(rB.y), x12 = h2f2(rB.z), x13 = h2f2(rB.w);
    float2 x20 = h2f2(rC.x), x21 = h2f2(rC.y), x22 = h2f2(rC.z), x23 = h2f2(rC.w);
    float2 x30 = h2f2(rD.x), x31 = h2f2(rD.y), x32 = h2f2(rD.z), x33 = h2f2(rD.w);
    float2 x40 = h2f2(rE.x), x41 = h2f2(rE.y), x42 = h2f2(rE.z), x43 = h2f2(rE.w);
    float2 x50 = h2f2(rF.x), x51 = h2f2(rF.y), x52 = h2f2(rF.z), x53 = h2f2(rF.w);
    float2 x60 = h2f2(rG.x), x61 = h2f2(rG.y), x62 = h2f2(rG.z), x63 = h2f2(rG.w);
    float2 x70 = h2f2(rH.x), x71 = h2f2(rH.y), x72 = h2f2(rH.z), x73 = h2f2(rH.w);

    FFT_STAGES(ALL8)
    FIN(x00,x01,x02,x03) FIN(x10,x11,x12,x13)
    FIN(x20,x21,x22,x23) FIN(x30,x31,x32,x33)
    FIN(x40,x41,x42,x43) FIN(x50,x51,x52,x53)
    FIN(x60,x61,x62,x63) FIN(x70,x71,x72,x73)

    float2* slot = Fb + (wv << 9);
    int nb = (int)bitrev6((unsigned)lane);
    STORE_GATHER(0, x00,x01,x02,x03, x10,x11,x12,x13)
    STORE_GATHER(1, x20,x21,x22,x23, x30,x31,x32,x33)
    STORE_GATHER(2, x40,x41,x42,x43, x50,x51,x52,x53)
    STORE_GATHER(3, x60,x61,x62,x63, x70,x71,x72,x73)
    __syncthreads();

    for (int i = tid; i < NSEG * 3; i += 512) {
        float v = accl[i];
        if (v != 0.f) atomicAdd(&acc[i], v);
    }
}

// ---------------------------------------------------------------------------
__global__ void final_kernel(const float* __restrict__ acc, const float* __restrict__ w,
                             float* __restrict__ out, float scale) {
    int lane = threadIdx.x;
    float val = 0.f;
    for (int s = lane; s < NSEG; s += 64) {
        float cr = acc[s * 3 + 0];
        float p1 = acc[s * 3 + 1];
        float p2 = acc[s * 3 + 2];
        float den = p1 * p2;
        float curve = den > 0.f ? fabsf(cr) * rsqrtf(den) : 0.f;
        val += curve * w[s + 1];
    }
    if (lane == 0) val += w[0];
    #pragma unroll
    for (int off = 32; off > 0; off >>= 1) val += __shfl_down(val, off);
    if (lane == 0) out[0] = scale * val;
}

// ---------------------------------------------------------------------------
extern "C" void kernel_launch(void* const* d_in, const int* in_sizes, int n_in,
                              void* d_out, int out_size, void* d_ws, size_t ws_size,
                              hipStream_t stream)
{
    const float* inp = (const float*)d_in[0];
    const float* tgt = (const float*)d_in[1];
    const float* wts = (const float*)d_in[2];
    const int*   rr  = (const int*)d_in[3];
    const int*   cc  = (const int*)d_in[4];
    const int*   sg  = (const int*)d_in[5];
    int npts   = in_sizes[3];
    int npairs = in_sizes[0] >> 16;               // B*C (65536 px/img)

    char* ws = (char*)d_ws;
    float* acc    = (float*)(ws + 0);             // 378 floats
    int*   starts = (int*)(ws + 2048);            // 129 ints
    int*   b_pack = (int*)(ws + 4096);
    size_t goff = 4096 + (size_t)npts * 4;
    goff = (goff + 255) & ~(size_t)255;
    unsigned* G = (unsigned*)(ws + goff);

    size_t per_pair = (size_t)256 * 256 * 4;      // 256 KiB (half2 as uint)
    int maxchunk = (int)((ws_size > goff ? (ws_size - goff) : 0) / per_pair);
    if (maxchunk < 1) maxchunk = 1;
    if (maxchunk > npairs) maxchunk = npairs;

    prep_all<<<1, 1024, 0, stream>>>(rr, cc, sg, npts, starts, b_pack, acc);

    for (int pb = 0; pb < npairs; pb += maxchunk) {
        int cp = npairs - pb < maxchunk ? npairs - pb : maxchunk;
        rowfft_kernel<<<cp * 8, 512, 0, stream>>>(inp, tgt, G, pb);
        colfft_gather_kernel<<<cp * 4, 512, 0, stream>>>(G, starts, b_pack, acc);
    }

    final_kernel<<<1, 64, 0, stream>>>(acc, wts, (float*)d_out, (float)npairs);
}

// Round 16
// 239.359 us; speedup vs baseline: 1.0028x; 1.0028x over previous
//
#include <hip/hip_runtime.h>
#include <hip/hip_fp16.h>
#include <math.h>

#define NSEG 126
#define PI_F 3.14159265358979323846f
#define SCHED_FENCE() __builtin_amdgcn_sched_barrier(0)

__device__ __forceinline__ unsigned bitrev8(unsigned v) { return __brev(v) >> 24; }
__device__ __forceinline__ unsigned bitrev6(unsigned v) { return __brev(v) >> 26; }
__device__ __forceinline__ float2 cmulc(float2 a, float2 b) {
    return make_float2(a.x*b.x - a.y*b.y, a.x*b.y + a.y*b.x);
}
__device__ __forceinline__ float2 mulmi(float2 a){ return make_float2(a.y, -a.x); }
__device__ __forceinline__ float2 h2f2(unsigned u) {
    __half2 h = __builtin_bit_cast(__half2, u);
    return __half22float2(h);
}
__device__ __forceinline__ unsigned f2h2(float2 v) {
    return __builtin_bit_cast(unsigned, __float22half2_rn(v));
}

// ---------------------------------------------------------------------------
// Fully scalarized v2 FFT (layout p = 4*lane + i, exit var_ki = X[bitrev8(p)]).
// ---------------------------------------------------------------------------
#define BFLY(v, W) { float px_=__shfl_xor(v.x,HL), py_=__shfl_xor(v.y,HL); \
  if (up) { float dx_=px_-v.x, dy_=py_-v.y; v=make_float2(dx_*W.x-dy_*W.y, dx_*W.y+dy_*W.x); } \
  else    { v=make_float2(v.x+px_, v.y+py_); } }

#define ROW4(a,b,c,d) BFLY(a,w0) BFLY(b,w1) BFLY(c,w2) BFLY(d,w3)

#define FFT_STAGES(ALL) \
  { const int HL=32; const bool up=(lane&32)!=0; float s_,c_; \
    __sincosf(-PI_F*(float)(lane&31)*(1.0f/32.0f),&s_,&c_); \
    float2 w0=make_float2(c_,s_); \
    float2 w1=cmulc(w0,make_float2(0.99969882f,-0.02454123f)); \
    float2 w2=cmulc(w0,make_float2(0.99879546f,-0.04906767f)); \
    float2 w3=cmulc(w0,make_float2(0.99729046f,-0.07356456f)); ALL } \
  { const int HL=16; const bool up=(lane&16)!=0; float s_,c_; \
    __sincosf(-PI_F*(float)(lane&15)*(1.0f/16.0f),&s_,&c_); \
    float2 w0=make_float2(c_,s_); \
    float2 w1=cmulc(w0,make_float2(0.99879546f,-0.04906767f)); \
    float2 w2=cmulc(w0,make_float2(0.99518473f,-0.09801714f)); \
    float2 w3=cmulc(w0,make_float2(0.98917651f,-0.14673047f)); ALL } \
  { const int HL=8; const bool up=(lane&8)!=0; float s_,c_; \
    __sincosf(-PI_F*(float)(lane&7)*(1.0f/8.0f),&s_,&c_); \
    float2 w0=make_float2(c_,s_); \
    float2 w1=cmulc(w0,make_float2(0.99518473f,-0.09801714f)); \
    float2 w2=cmulc(w0,make_float2(0.98078528f,-0.19509032f)); \
    float2 w3=cmulc(w0,make_float2(0.95694034f,-0.29028468f)); ALL } \
  { const int HL=4; const bool up=(lane&4)!=0; float s_,c_; \
    __sincosf(-PI_F*(float)(lane&3)*(1.0f/4.0f),&s_,&c_); \
    float2 w0=make_float2(c_,s_); \
    float2 w1=cmulc(w0,make_float2(0.98078528f,-0.19509032f)); \
    float2 w2=cmulc(w0,make_float2(0.92387953f,-0.38268343f)); \
    float2 w3=cmulc(w0,make_float2(0.83146961f,-0.55557023f)); ALL } \
  { const int HL=2; const bool up=(lane&2)!=0; \
    float2 w0=(lane&1)?make_float2(0.f,-1.f):make_float2(1.f,0.f); \
    float2 w1=cmulc(w0,make_float2(0.92387953f,-0.38268343f)); \
    float2 w2=cmulc(w0,make_float2(0.70710678f,-0.70710678f)); \
    float2 w3=cmulc(w0,make_float2(0.38268343f,-0.92387953f)); ALL } \
  { const int HL=1; const bool up=(lane&1)!=0; \
    float2 w0=make_float2(1.f,0.f); \
    float2 w1=make_float2(0.70710678f,-0.70710678f); \
    float2 w2=make_float2(0.f,-1.f); \
    float2 w3=make_float2(-0.70710678f,-0.70710678f); ALL }

#define FIN(a0,a1,a2,a3) { float2 u_,v_; \
  u_=a0; v_=a2; a0=make_float2(u_.x+v_.x,u_.y+v_.y); a2=make_float2(u_.x-v_.x,u_.y-v_.y); \
  u_=a1; v_=a3; a1=make_float2(u_.x+v_.x,u_.y+v_.y); a3=mulmi(make_float2(u_.x-v_.x,u_.y-v_.y)); \
  u_=a0; v_=a1; a0=make_float2(u_.x+v_.x,u_.y+v_.y); a1=make_float2(u_.x-v_.x,u_.y-v_.y); \
  u_=a2; v_=a3; a2=make_float2(u_.x+v_.x,u_.y+v_.y); a3=make_float2(u_.x-v_.x,u_.y-v_.y); }

// ---------------------------------------------------------------------------
// Fused prep (R11 format): bucket j = 255-c; pack r | mirror(r)<<8 | seg<<16.
// ---------------------------------------------------------------------------
__global__ __launch_bounds__(1024) void prep_all(
    const int* __restrict__ rr, const int* __restrict__ cc,
    const int* __restrict__ seg, int n,
    int* __restrict__ starts, int* __restrict__ b_pack, float* __restrict__ acc)
{
    __shared__ int cnt[128];
    __shared__ int cur[128];
    int tid = threadIdx.x;
    if (tid < NSEG * 3) acc[tid] = 0.f;
    if (tid < 128) cnt[tid] = 0;
    __syncthreads();
    for (int i = tid; i < n; i += 1024) {
        int c = cc[i], r = rr[i];
        if ((c > 128) || (c == 128 && r > 128)) atomicAdd(&cnt[255 - c], 1);
    }
    __syncthreads();
    if (tid < 64) {
        int2 c2 = reinterpret_cast<const int2*>(cnt)[tid];
        int lsum = c2.x + c2.y;
        int pre = lsum;
        #pragma unroll
        for (int off = 1; off < 64; off <<= 1) {
            int v = __shfl_up(pre, off);
            if (tid >= off) pre += v;
        }
        int excl = pre - lsum;
        int2 outv = make_int2(excl, excl + c2.x);
        reinterpret_cast<int2*>(cur)[tid] = outv;
        reinterpret_cast<int2*>(starts)[tid] = outv;
        if (tid == 63) starts[128] = excl + c2.x + c2.y;
    }
    __syncthreads();
    for (int i = tid; i < n; i += 1024) {
        int c = cc[i], r = rr[i];
        if ((c > 128) || (c == 128 && r > 128)) {
            int j = 255 - c;
            int pos = atomicAdd(&cur[j], 1);
            b_pack[pos] = r | (((256 - r) & 255) << 8) | (seg[i] << 16);
        }
    }
}

// ---------------------------------------------------------------------------
// Row-pass: scalarized v2 FFT + load fence (all 8 global loads issue first).
// ---------------------------------------------------------------------------
#define ALL4 ROW4(x00,x01,x02,x03) ROW4(x10,x11,x12,x13) \
             ROW4(x20,x21,x22,x23) ROW4(x30,x31,x32,x33)

__global__ __launch_bounds__(512, 1) void rowfft_kernel(
    const float* __restrict__ inp, const float* __restrict__ tgt,
    unsigned* __restrict__ G, int pair_base)
{
    __shared__ unsigned T[256 * 17];             // 17408 B
    int tid    = threadIdx.x;
    int wv     = tid >> 6;
    int lane   = tid & 63;
    int plocal = blockIdx.x >> 3;
    int rowgrp = blockIdx.x & 7;
    int row0   = (rowgrp << 5) + (wv << 2);
    size_t base = (((size_t)(pair_base + plocal)) << 16) + ((size_t)row0 << 8);
    const float4* s1 = (const float4*)(inp + base);
    const float4* s2 = (const float4*)(tgt + base);

    float4 A0 = s1[lane],       B0 = s2[lane];
    float4 A1 = s1[64 + lane],  B1 = s2[64 + lane];
    float4 A2 = s1[128 + lane], B2 = s2[128 + lane];
    float4 A3 = s1[192 + lane], B3 = s2[192 + lane];
    SCHED_FENCE();                               // all 8 loads issue before FFT

    float2 x00 = make_float2(A0.x, B0.x), x01 = make_float2(A0.y, B0.y),
           x02 = make_float2(A0.z, B0.z), x03 = make_float2(A0.w, B0.w);
    float2 x10 = make_float2(A1.x, B1.x), x11 = make_float2(A1.y, B1.y),
           x12 = make_float2(A1.z, B1.z), x13 = make_float2(A1.w, B1.w);
    float2 x20 = make_float2(A2.x, B2.x), x21 = make_float2(A2.y, B2.y),
           x22 = make_float2(A2.z, B2.z), x23 = make_float2(A2.w, B2.w);
    float2 x30 = make_float2(A3.x, B3.x), x31 = make_float2(A3.y, B3.y),
           x32 = make_float2(A3.z, B3.z), x33 = make_float2(A3.w, B3.w);

    FFT_STAGES(ALL4)
    FIN(x00,x01,x02,x03) FIN(x10,x11,x12,x13)
    FIN(x20,x21,x22,x23) FIN(x30,x31,x32,x33)

    unsigned* dst = G + (((size_t)plocal) << 16) + (rowgrp << 5);
    #pragma unroll
    for (int pass = 0; pass < 2; pass++) {
        if ((wv >> 2) == pass) {
            int xr = ((wv & 3) << 2);
            unsigned* Tp = &T[(4 * lane) * 17 + xr];
            Tp[0]  = f2h2(x00); Tp[17] = f2h2(x01); Tp[34] = f2h2(x02); Tp[51] = f2h2(x03);
            Tp[1]  = f2h2(x10); Tp[18] = f2h2(x11); Tp[35] = f2h2(x12); Tp[52] = f2h2(x13);
            Tp[2]  = f2h2(x20); Tp[19] = f2h2(x21); Tp[36] = f2h2(x22); Tp[53] = f2h2(x23);
            Tp[3]  = f2h2(x30); Tp[20] = f2h2(x31); Tp[37] = f2h2(x32); Tp[54] = f2h2(x33);
        }
        __syncthreads();
        int xl = tid & 15;
        int qq = tid >> 4;
        #pragma unroll
        for (int ii = 0; ii < 8; ii++) {
            int q = qq + (ii << 5);
            dst[q * 256 + (pass << 4) + xl] = T[q * 17 + xl];
        }
        __syncthreads();
    }
}

// ---------------------------------------------------------------------------
// Column-pass + gather: scalarized + load fence (8 dwordx4 in flight).
// ---------------------------------------------------------------------------
#define ALL8 ROW4(x00,x01,x02,x03) ROW4(x10,x11,x12,x13) \
             ROW4(x20,x21,x22,x23) ROW4(x30,x31,x32,x33) \
             ROW4(x40,x41,x42,x43) ROW4(x50,x51,x52,x53) \
             ROW4(x60,x61,x62,x63) ROW4(x70,x71,x72,x73)

#define STORE_GATHER(t, A0,A1,A2,A3, B0,B1,B2,B3) { \
    slot[nb]       = A0; slot[nb + 128]       = A1; \
    slot[nb + 64]  = A2; slot[nb + 192]       = A3; \
    slot[256 + nb] = B0; slot[256 + nb + 128] = B1; \
    slot[256 + nb + 64] = B2; slot[256 + nb + 192] = B3; \
    int j_ = jb0 + (t); \
    int s0_ = starts[j_], s1_ = starts[j_ + 1]; \
    int e_  = s0_ + lane; \
    int pk_ = (e_ < s1_) ? b_pack[e_] : 0; \
    while (e_ < s1_) { \
        int e2_  = e_ + 64; \
        int pk2_ = (e2_ < s1_) ? b_pack[e2_] : 0; \
        float2 a_ = slot[256 + (pk_ & 255)]; \
        float2 m_ = slot[(pk_ >> 8) & 255]; \
        int sg_ = pk_ >> 16; \
        float f1x_ = a_.x + m_.x, f1y_ = a_.y - m_.y; \
        float dx_  = a_.x - m_.x, dy_  = a_.y + m_.y; \
        atomicAdd(&accl[sg_ * 3 + 0], f1x_ * dy_ - f1y_ * dx_); \
        atomicAdd(&accl[sg_ * 3 + 1], f1x_ * f1x_ + f1y_ * f1y_); \
        atomicAdd(&accl[sg_ * 3 + 2], dx_ * dx_ + dy_ * dy_); \
        e_ = e2_; pk_ = pk2_; \
    } }

__global__ __launch_bounds__(512, 1) void colfft_gather_kernel(
    const unsigned* __restrict__ G, const int* __restrict__ starts,
    const int* __restrict__ b_pack, float* __restrict__ acc)
{
    __shared__ float2 Fb[8 * 512];               // 32 KiB
    __shared__ float accl[NSEG * 3];
    int tid    = threadIdx.x;
    int wv     = tid >> 6;
    int lane   = tid & 63;
    int plocal = blockIdx.x >> 2;
    int b      = blockIdx.x & 3;
    int jb0    = (b << 5) + (wv << 2);

    for (int i = tid; i < NSEG * 3; i += 512) accl[i] = 0.f;
    __syncthreads();

    const unsigned* Gp = G + (((size_t)plocal) << 16);
    const uint4* cA = (const uint4*)(Gp + ((size_t)bitrev8((unsigned)(jb0 + 1)) << 8));
    const uint4* cB = (const uint4*)(Gp + ((size_t)bitrev8((unsigned)(255 - jb0)) << 8));
    const uint4* cC = (const uint4*)(Gp + ((size_t)bitrev8((unsigned)(jb0 + 2)) << 8));
    const uint4* cD = (const uint4*)(Gp + ((size_t)bitrev8((unsigned)(254 - jb0)) << 8));
    const uint4* cE = (const uint4*)(Gp + ((size_t)bitrev8((unsigned)(jb0 + 3)) << 8));
    const uint4* cF = (const uint4*)(Gp + ((size_t)bitrev8((unsigned)(253 - jb0)) << 8));
    const uint4* cG = (const uint4*)(Gp + ((size_t)bitrev8((unsigned)(jb0 + 4)) << 8));
    const uint4* cH = (const uint4*)(Gp + ((size_t)bitrev8((unsigned)(252 - jb0)) << 8));
    uint4 rA = cA[lane], rB = cB[lane], rC = cC[lane], rD = cD[lane];
    uint4 rE = cE[lane], rF = cF[lane], rG = cG[lane], rH = cH[lane];
    SCHED_FENCE();                               // all 8 loads issue before FFT

    float2 x00 = h2f2(rA.x), x01 = h2f2(rA.y), x02 = h2f2(rA.z), x03 = h2f2(rA.w);
    float2 x10 = h2f2(rB.x), x11 = h2f2(rB.y), x12 = h2f2(rB.z), x13 = h2f2(rB.w);
    float2 x20 = h2f2(rC.x), x21 = h2f2(rC.y), x22 = h2f2(rC.z), x23 = h2f2(rC.w);
    float2 x30 = h2f2(rD.x), x31 = h2f2(rD.y), x32 = h2f2(rD.z), x33 = h2f2(rD.w);
    float2 x40 = h2f2(rE.x), x41 = h2f2(rE.y), x42 = h2f2(rE.z), x43 = h2f2(rE.w);
    float2 x50 = h2f2(rF.x), x51 = h2f2(rF.y), x52 = h2f2(rF.z), x53 = h2f2(rF.w);
    float2 x60 = h2f2(rG.x), x61 = h2f2(rG.y), x62 = h2f2(rG.z), x63 = h2f2(rG.w);
    float2 x70 = h2f2(rH.x), x71 = h2f2(rH.y), x72 = h2f2(rH.z), x73 = h2f2(rH.w);

    FFT_STAGES(ALL8)
    FIN(x00,x01,x02,x03) FIN(x10,x11,x12,x13)
    FIN(x20,x21,x22,x23) FIN(x30,x31,x32,x33)
    FIN(x40,x41,x42,x43) FIN(x50,x51,x52,x53)
    FIN(x60,x61,x62,x63) FIN(x70,x71,x72,x73)

    float2* slot = Fb + (wv << 9);
    int nb = (int)bitrev6((unsigned)lane);
    STORE_GATHER(0, x00,x01,x02,x03, x10,x11,x12,x13)
    STORE_GATHER(1, x20,x21,x22,x23, x30,x31,x32,x33)
    STORE_GATHER(2, x40,x41,x42,x43, x50,x51,x52,x53)
    STORE_GATHER(3, x60,x61,x62,x63, x70,x71,x72,x73)
    __syncthreads();

    for (int i = tid; i < NSEG * 3; i += 512) {
        float v = accl[i];
        if (v != 0.f) atomicAdd(&acc[i], v);
    }
}

// ---------------------------------------------------------------------------
__global__ void final_kernel(const float* __restrict__ acc, const float* __restrict__ w,
                             float* __restrict__ out, float scale) {
    int lane = threadIdx.x;
    float val = 0.f;
    for (int s = lane; s < NSEG; s += 64) {
        float cr = acc[s * 3 + 0];
        float p1 = acc[s * 3 + 1];
        float p2 = acc[s * 3 + 2];
        float den = p1 * p2;
        float curve = den > 0.f ? fabsf(cr) * rsqrtf(den) : 0.f;
        val += curve * w[s + 1];
    }
    if (lane == 0) val += w[0];
    #pragma unroll
    for (int off = 32; off > 0; off >>= 1) val += __shfl_down(val, off);
    if (lane == 0) out[0] = scale * val;
}

// ---------------------------------------------------------------------------
extern "C" void kernel_launch(void* const* d_in, const int* in_sizes, int n_in,
                              void* d_out, int out_size, void* d_ws, size_t ws_size,
                              hipStream_t stream)
{
    const float* inp = (const float*)d_in[0];
    const float* tgt = (const float*)d_in[1];
    const float* wts = (const float*)d_in[2];
    const int*   rr  = (const int*)d_in[3];
    const int*   cc  = (const int*)d_in[4];
    const int*   sg  = (const int*)d_in[5];
    int npts   = in_sizes[3];
    int npairs = in_sizes[0] >> 16;               // B*C (65536 px/img)

    char* ws = (char*)d_ws;
    float* acc    = (float*)(ws + 0);             // 378 floats
    int*   starts = (int*)(ws + 2048);            // 129 ints
    int*   b_pack = (int*)(ws + 4096);
    size_t goff = 4096 + (size_t)npts * 4;
    goff = (goff + 255) & ~(size_t)255;
    unsigned* G = (unsigned*)(ws + goff);

    size_t per_pair = (size_t)256 * 256 * 4;      // 256 KiB (half2 as uint)
    int maxchunk = (int)((ws_size > goff ? (ws_size - goff) : 0) / per_pair);
    if (maxchunk < 1) maxchunk = 1;
    if (maxchunk > npairs) maxchunk = npairs;

    prep_all<<<1, 1024, 0, stream>>>(rr, cc, sg, npts, starts, b_pack, acc);

    for (int pb = 0; pb < npairs; pb += maxchunk) {
        int cp = npairs - pb < maxchunk ? npairs - pb : maxchunk;
        rowfft_kernel<<<cp * 8, 512, 0, stream>>>(inp, tgt, G, pb);
        colfft_gather_kernel<<<cp * 4, 512, 0, stream>>>(G, starts, b_pack, acc);
    }

    final_kernel<<<1, 64, 0, stream>>>(acc, wts, (float*)d_out, (float)npairs);
}